// Round 2
// baseline (1125.270 us; speedup 1.0000x reference)
//
#include <hip/hip_runtime.h>
#include <cstdint>

typedef _Float16 f16;
typedef _Float16 f16x4 __attribute__((ext_vector_type(4)));
typedef _Float16 f16x8 __attribute__((ext_vector_type(8)));
typedef float f32x4 __attribute__((ext_vector_type(4)));

#define MFMA16(a, b, c) __builtin_amdgcn_mfma_f32_16x16x32_f16((a), (b), (c), 0, 0, 0)

__device__ __forceinline__ float gelu_f(float x) {
    return 0.5f * x * (1.0f + erff(x * 0.70710678118654752440f));
}

__device__ __forceinline__ void load_lds16(const void* g, void* l) {
    __builtin_amdgcn_global_load_lds(
        (const __attribute__((address_space(1))) void*)(uintptr_t)g,
        (__attribute__((address_space(3))) void*)(uint32_t)(uintptr_t)l,
        16, 0, 0);
}

// ---------------- prep: fp32 weights -> fp16 (with padding) ----------------
// W1p [512][800] (K pad 784->800, zeros), W2f[256][512], W3f[128][256],
// W4f[64][128], W5f[32][64], W6p[16][32] (rows 10..15 zero), Wrf[16][256]
__global__ void k_prep(const float* __restrict__ W1, const float* __restrict__ W2,
                       const float* __restrict__ W3, const float* __restrict__ W4,
                       const float* __restrict__ W5, const float* __restrict__ W6,
                       const float* __restrict__ Wr,
                       f16* __restrict__ W1p, f16* __restrict__ W2f, f16* __restrict__ W3f,
                       f16* __restrict__ W4f, f16* __restrict__ W5f, f16* __restrict__ W6p,
                       f16* __restrict__ Wrf) {
    int i = blockIdx.x * 256 + threadIdx.x;
    if (i < 409600) {
        int r = i / 800, c = i - r * 800;
        W1p[i] = (f16)(c < 784 ? W1[r * 784 + c] : 0.0f);
        return;
    }
    i -= 409600;
    if (i < 131072) { W2f[i] = (f16)W2[i]; return; }
    i -= 131072;
    if (i < 32768) { W3f[i] = (f16)W3[i]; return; }
    i -= 32768;
    if (i < 8192) { W4f[i] = (f16)W4[i]; return; }
    i -= 8192;
    if (i < 2048) { W5f[i] = (f16)W5[i]; return; }
    i -= 2048;
    if (i < 512) {
        int r = i >> 5, c = i & 31;
        W6p[i] = (f16)(r < 10 ? W6[r * 32 + c] : 0.0f);
        return;
    }
    i -= 512;
    if (i < 4096) { Wrf[i] = (f16)Wr[i]; return; }
}

// ---------------- xcvt: X fp32 [B][784] -> X16 fp16 [B][800] (K-padded) ----
__global__ __launch_bounds__(256)
void k_xcvt(const float* __restrict__ X, f16* __restrict__ X16) {
    const size_t t = (size_t)blockIdx.x * 256 + threadIdx.x; // B*200 threads
    const size_t row = t / 200;
    const int c4 = (int)(t - row * 200) * 4;
    f16x4 v = {0, 0, 0, 0};
    if (c4 < 784) {
        const float4 f = *(const float4*)(X + row * 784 + c4);
        v[0] = (f16)f.x; v[1] = (f16)f.y; v[2] = (f16)f.z; v[3] = (f16)f.w;
    }
    *(f16x4*)(X16 + row * 800 + c4) = v;
}

// ---------------- GEMM1: H1 = gelu(X16 @ W1p^T + b1), all fp16 ------------
__global__ __launch_bounds__(256, 2)
void k_gemm1(const f16* __restrict__ A, const f16* __restrict__ W1p,
             const float* __restrict__ b1, f16* __restrict__ H1) {
    __shared__ f16 As[128 * 32];
    __shared__ f16 Bs[128 * 32];
    const int tid = threadIdx.x;
    const int wave = tid >> 6, lane = tid & 63;
    const int nt = blockIdx.x & 3;           // 512 / 128
    const size_t mt = blockIdx.x >> 2;
    const size_t row0 = mt * 128;
    const int col0 = nt * 128;
    const int am = lane & 15, akg = lane >> 4, ak = akg * 8;
    const int wm = (wave & 1) * 64, wn = (wave >> 1) * 64;
    const f32x4 zero4 = {0.f, 0.f, 0.f, 0.f};
    f32x4 acc[4][4];
#pragma unroll
    for (int i = 0; i < 4; ++i)
#pragma unroll
        for (int j = 0; j < 4; ++j) acc[i][j] = zero4;

    const int inst0 = wave * 2;
    const int srow = lane >> 2;
    const int scol = (lane & 3) * 8;

    for (int kt = 0; kt < 25; ++kt) {
        const int kb = kt * 32;
#pragma unroll
        for (int i = 0; i < 2; ++i) {
            const int inst = inst0 + i;
            load_lds16(A + (row0 + inst * 16 + srow) * 800 + kb + scol, &As[inst * 512]);
            load_lds16(W1p + (size_t)(col0 + inst * 16 + srow) * 800 + kb + scol, &Bs[inst * 512]);
        }
        __syncthreads();
        f16x8 af[4], bf[4];
#pragma unroll
        for (int i = 0; i < 4; ++i) af[i] = *(const f16x8*)&As[(wm + i * 16 + am) * 32 + ak];
#pragma unroll
        for (int j = 0; j < 4; ++j) bf[j] = *(const f16x8*)&Bs[(wn + j * 16 + am) * 32 + ak];
#pragma unroll
        for (int i = 0; i < 4; ++i)
#pragma unroll
            for (int j = 0; j < 4; ++j)
                acc[i][j] = MFMA16(af[i], bf[j], acc[i][j]);
        __syncthreads();
    }
    const int cr = akg * 4;
#pragma unroll
    for (int j = 0; j < 4; ++j) {
        const int col = col0 + wn + j * 16 + am;
        const float bias = b1[col];
#pragma unroll
        for (int i = 0; i < 4; ++i) {
            const size_t row = row0 + wm + i * 16 + cr;
#pragma unroll
            for (int r = 0; r < 4; ++r)
                H1[(row + r) * 512 + col] = (f16)gelu_f(acc[i][j][r] + bias);
        }
    }
}

// ---------------- GEMM2: MID = gelu(H1 @ W2^T + b2), all fp16 --------------
__global__ __launch_bounds__(256, 2)
void k_gemm2(const f16* __restrict__ A, const f16* __restrict__ W2f,
             const float* __restrict__ b2, f16* __restrict__ Cout) {
    __shared__ f16 As[128 * 32];
    __shared__ f16 Bs[128 * 32];
    const int tid = threadIdx.x;
    const int wave = tid >> 6, lane = tid & 63;
    const int nt = blockIdx.x & 1;           // 256 / 128
    const size_t mt = blockIdx.x >> 1;
    const size_t row0 = mt * 128;
    const int col0 = nt * 128;
    const int am = lane & 15, akg = lane >> 4, ak = akg * 8;
    const int wm = (wave & 1) * 64, wn = (wave >> 1) * 64;
    const f32x4 zero4 = {0.f, 0.f, 0.f, 0.f};
    f32x4 acc[4][4];
#pragma unroll
    for (int i = 0; i < 4; ++i)
#pragma unroll
        for (int j = 0; j < 4; ++j) acc[i][j] = zero4;

    const int inst0 = wave * 2;
    const int srow = lane >> 2;
    const int scol = (lane & 3) * 8;

    for (int kt = 0; kt < 16; ++kt) {
        const int kb = kt * 32;
#pragma unroll
        for (int i = 0; i < 2; ++i) {
            const int inst = inst0 + i;
            load_lds16(A + (row0 + inst * 16 + srow) * 512 + kb + scol, &As[inst * 512]);
            load_lds16(W2f + (size_t)(col0 + inst * 16 + srow) * 512 + kb + scol, &Bs[inst * 512]);
        }
        __syncthreads();
        f16x8 af[4], bf[4];
#pragma unroll
        for (int i = 0; i < 4; ++i) af[i] = *(const f16x8*)&As[(wm + i * 16 + am) * 32 + ak];
#pragma unroll
        for (int j = 0; j < 4; ++j) bf[j] = *(const f16x8*)&Bs[(wn + j * 16 + am) * 32 + ak];
#pragma unroll
        for (int i = 0; i < 4; ++i)
#pragma unroll
            for (int j = 0; j < 4; ++j)
                acc[i][j] = MFMA16(af[i], bf[j], acc[i][j]);
        __syncthreads();
    }
    const int cr = akg * 4;
#pragma unroll
    for (int j = 0; j < 4; ++j) {
        const int col = col0 + wn + j * 16 + am;
        const float bias = b2[col];
#pragma unroll
        for (int i = 0; i < 4; ++i) {
            const size_t row = row0 + wm + i * 16 + cr;
#pragma unroll
            for (int r = 0; r < 4; ++r)
                Cout[(row + r) * 256 + col] = (f16)gelu_f(acc[i][j][r] + bias);
        }
    }
}

// ---------------- fused tail: router + grouped fc3 + L4 + L5 + L6 ----------
// 64 rows/block, 4 waves, each wave owns 16 rows; all intermediates in LDS.
__global__ __launch_bounds__(256, 2)
void k_tail(const f16* __restrict__ MID,
            const f16* __restrict__ W3f, const float* __restrict__ b3,
            const f16* __restrict__ W4f, const float* __restrict__ b4,
            const f16* __restrict__ W5f, const float* __restrict__ b5,
            const f16* __restrict__ W6p, const float* __restrict__ b6v,
            const f16* __restrict__ Wrf, const float* __restrict__ brv,
            float* __restrict__ OUT) {
    __shared__ f16 s_mid[64 * 264];     // mid_in tile, stride 264 (+8 pad)
    __shared__ float s_pw[64 * 20];     // 16 pathway weights + 4 group-sums
    __shared__ f16 s_mo[64 * 136];      // mid_out, stride 136
    __shared__ f16 s_h4[64 * 72];       // h4, stride 72
    __shared__ f16 s_h5[64 * 40];       // h5, stride 40
    const int tid = threadIdx.x, wave = tid >> 6, lane = tid & 63;
    const size_t r0 = (size_t)blockIdx.x * 64;
    const int am = lane & 15, akg = lane >> 4, ak = akg * 8;
    const int wr = wave * 16;           // wave's row base (wave-local rows)
    const int crow = wr + akg * 4;      // lane's first accumulator row
    const f32x4 zero4 = {0.f, 0.f, 0.f, 0.f};

    // phase 1: stage mid_in [64][256] -> LDS (padded stride)
    {
        const int row = tid >> 2, seg = (tid & 3) * 64;
        const f16* src = MID + (r0 + row) * 256 + seg;
        f16* dst = s_mid + row * 264 + seg;
#pragma unroll
        for (int c = 0; c < 8; ++c)
            *(f16x8*)(dst + c * 8) = *(const f16x8*)(src + c * 8);
    }
    __syncthreads();

    // phase 2: router logits (MFMA, N=16, K=256) + softmax across 16 lanes
    {
        f32x4 lacc = zero4;
#pragma unroll
        for (int ks = 0; ks < 8; ++ks) {
            f16x8 a = *(const f16x8*)(s_mid + (wr + am) * 264 + ks * 32 + ak);
            f16x8 b = *(const f16x8*)(Wrf + am * 256 + ks * 32 + ak);
            lacc = MFMA16(a, b, lacc);
        }
        const float brn = brv[am];
#pragma unroll
        for (int r = 0; r < 4; ++r) {
            float l = lacc[r] + brn;    // logit[row=crow+r][p=am]
            float mx = l;
#pragma unroll
            for (int m = 1; m <= 8; m <<= 1) mx = fmaxf(mx, __shfl_xor(mx, m));
            const float e = __expf(l - mx);
            float s = e;
#pragma unroll
            for (int m = 1; m <= 8; m <<= 1) s += __shfl_xor(s, m);
            const float p = e / s;      // pathway p = g*4 + o (o=am&3, g=am>>2)
            float sg = p;               // sum over g for fixed o
            sg += __shfl_xor(sg, 4);
            sg += __shfl_xor(sg, 8);
            s_pw[(crow + r) * 20 + am] = p;
            if (am < 4) s_pw[(crow + r) * 20 + 16 + am] = sg;
        }
    }
    __syncthreads();

    // phase 3: grouped fc3 + pathway-weighted combine + gelu -> s_mo
    {
        f16x8 a3[4][2];
#pragma unroll
        for (int g = 0; g < 4; ++g)
#pragma unroll
            for (int kh = 0; kh < 2; ++kh)
                a3[g][kh] = *(const f16x8*)(s_mid + (wr + am) * 264 + g * 64 + kh * 32 + ak);
#pragma unroll
        for (int o = 0; o < 4; ++o) {
            float pwv[4][4], sgl[4];
#pragma unroll
            for (int r = 0; r < 4; ++r) {
                sgl[r] = s_pw[(crow + r) * 20 + 16 + o];
#pragma unroll
                for (int g = 0; g < 4; ++g)
                    pwv[g][r] = s_pw[(crow + r) * 20 + g * 4 + o];
            }
#pragma unroll
            for (int ctl = 0; ctl < 2; ++ctl) {
                const int ct = o * 2 + ctl;
                const int col = ct * 16 + am;
                const float bias = b3[col];
                f32x4 oacc;
#pragma unroll
                for (int r = 0; r < 4; ++r) oacc[r] = bias * sgl[r];
#pragma unroll
                for (int g = 0; g < 4; ++g) {
                    f32x4 t = zero4;
                    t = MFMA16(a3[g][0], *(const f16x8*)(W3f + (size_t)col * 256 + g * 64 + ak), t);
                    t = MFMA16(a3[g][1], *(const f16x8*)(W3f + (size_t)col * 256 + g * 64 + 32 + ak), t);
#pragma unroll
                    for (int r = 0; r < 4; ++r) oacc[r] += pwv[g][r] * t[r];
                }
#pragma unroll
                for (int r = 0; r < 4; ++r)
                    s_mo[(crow + r) * 136 + col] = (f16)gelu_f(oacc[r]);
            }
        }
    }
    __syncthreads();

    // phase 4: L4 = gelu(mid_out @ W4^T + b4), K=128 -> N=64
    {
        f16x8 a4[4];
#pragma unroll
        for (int ks = 0; ks < 4; ++ks)
            a4[ks] = *(const f16x8*)(s_mo + (wr + am) * 136 + ks * 32 + ak);
#pragma unroll
        for (int ct = 0; ct < 4; ++ct) {
            const int col = ct * 16 + am;
            f32x4 acc = zero4;
#pragma unroll
            for (int ks = 0; ks < 4; ++ks)
                acc = MFMA16(a4[ks], *(const f16x8*)(W4f + (size_t)col * 128 + ks * 32 + ak), acc);
            const float bias = b4[col];
#pragma unroll
            for (int r = 0; r < 4; ++r)
                s_h4[(crow + r) * 72 + col] = (f16)gelu_f(acc[r] + bias);
        }
    }
    __syncthreads();

    // phase 5: L5 = gelu(h4 @ W5^T + b5), K=64 -> N=32
    {
        f16x8 a5[2];
#pragma unroll
        for (int ks = 0; ks < 2; ++ks)
            a5[ks] = *(const f16x8*)(s_h4 + (wr + am) * 72 + ks * 32 + ak);
#pragma unroll
        for (int ct = 0; ct < 2; ++ct) {
            const int col = ct * 16 + am;
            f32x4 acc = zero4;
#pragma unroll
            for (int ks = 0; ks < 2; ++ks)
                acc = MFMA16(a5[ks], *(const f16x8*)(W5f + (size_t)col * 64 + ks * 32 + ak), acc);
            const float bias = b5[col];
#pragma unroll
            for (int r = 0; r < 4; ++r)
                s_h5[(crow + r) * 40 + col] = (f16)gelu_f(acc[r] + bias);
        }
    }
    __syncthreads();

    // phase 6: L6 = h5 @ W6^T + b6, K=32 -> N=16 (cols 10..15 padded, unstored)
    {
        f16x8 a6 = *(const f16x8*)(s_h5 + (wr + am) * 40 + ak);
        f16x8 bw = *(const f16x8*)(W6p + am * 32 + ak);
        f32x4 acc = MFMA16(a6, bw, zero4);
        if (am < 10) {
            const float bb = b6v[am];
#pragma unroll
            for (int r = 0; r < 4; ++r)
                OUT[(r0 + crow + r) * 10 + am] = acc[r] + bb;
        }
    }
}

extern "C" void kernel_launch(void* const* d_in, const int* in_sizes, int n_in,
                              void* d_out, int out_size, void* d_ws, size_t ws_size,
                              hipStream_t stream) {
    const float* x  = (const float*)d_in[0];
    const float* W1 = (const float*)d_in[1];
    const float* b1 = (const float*)d_in[2];
    const float* W2 = (const float*)d_in[3];
    const float* b2 = (const float*)d_in[4];
    const float* W3 = (const float*)d_in[5];
    const float* b3 = (const float*)d_in[6];
    const float* W4 = (const float*)d_in[7];
    const float* b4 = (const float*)d_in[8];
    const float* W5 = (const float*)d_in[9];
    const float* b5 = (const float*)d_in[10];
    const float* W6 = (const float*)d_in[11];
    const float* b6 = (const float*)d_in[12];
    const float* Wr = (const float*)d_in[13];
    const float* br = (const float*)d_in[14];
    float* out = (float*)d_out;

    const int M = in_sizes[0] / 784;    // 131072

    char* ws = (char*)d_ws;
    f16* W1p = (f16*)ws; ws += 512 * 800 * 2;       // 819200
    f16* W2f = (f16*)ws; ws += 256 * 512 * 2;       // 262144
    f16* W3f = (f16*)ws; ws += 128 * 256 * 2;       // 65536
    f16* W4f = (f16*)ws; ws += 64 * 128 * 2;        // 16384
    f16* W5f = (f16*)ws; ws += 32 * 64 * 2;         // 4096
    f16* W6p = (f16*)ws; ws += 16 * 32 * 2;         // 1024
    f16* Wrf = (f16*)ws; ws += 16 * 256 * 2;        // 8192
    // X16 [M][800] fp16; MIDB aliases it (X16 dead once gemm1 completes)
    f16* X16 = (f16*)ws;
    f16* MIDB = (f16*)ws; ws += (size_t)M * 800 * 2; // 210 MB
    f16* H1  = (f16*)ws; ws += (size_t)M * 512 * 2;  // 134 MB

    k_prep<<<2298, 256, 0, stream>>>(W1, W2, W3, W4, W5, W6, Wr,
                                     W1p, W2f, W3f, W4f, W5f, W6p, Wrf);
    k_xcvt<<<(M * 200) / 256, 256, 0, stream>>>(x, X16);
    k_gemm1<<<(M / 128) * 4, 256, 0, stream>>>(X16, W1p, b1, H1);
    k_gemm2<<<(M / 128) * 2, 256, 0, stream>>>(H1, W2f, b2, MIDB);
    k_tail<<<M / 64, 256, 0, stream>>>(MIDB, W3f, b3, W4f, b4, W5f, b5,
                                       W6p, b6, Wrf, br, out);
}

// Round 3
// 985.345 us; speedup vs baseline: 1.1420x; 1.1420x over previous
//
#include <hip/hip_runtime.h>
#include <cstdint>

typedef _Float16 f16;
typedef _Float16 f16x4 __attribute__((ext_vector_type(4)));
typedef _Float16 f16x8 __attribute__((ext_vector_type(8)));
typedef float f32x4 __attribute__((ext_vector_type(4)));

#define MFMA16(a, b, c) __builtin_amdgcn_mfma_f32_16x16x32_f16((a), (b), (c), 0, 0, 0)

__device__ __forceinline__ float gelu_f(float x) {
    return 0.5f * x * (1.0f + erff(x * 0.70710678118654752440f));
}

__device__ __forceinline__ void load_lds16(const void* g, void* l) {
    __builtin_amdgcn_global_load_lds(
        (const __attribute__((address_space(1))) void*)(uintptr_t)g,
        (__attribute__((address_space(3))) void*)(uint32_t)(uintptr_t)l,
        16, 0, 0);
}

// ---------------- prep: fp32 weights -> fp16 (with padding) ----------------
__global__ void k_prep(const float* __restrict__ W1, const float* __restrict__ W2,
                       const float* __restrict__ W3, const float* __restrict__ W4,
                       const float* __restrict__ W5, const float* __restrict__ W6,
                       const float* __restrict__ Wr,
                       f16* __restrict__ W1p, f16* __restrict__ W2f, f16* __restrict__ W3f,
                       f16* __restrict__ W4f, f16* __restrict__ W5f, f16* __restrict__ W6p,
                       f16* __restrict__ Wrf) {
    int i = blockIdx.x * 256 + threadIdx.x;
    if (i < 409600) {
        int r = i / 800, c = i - r * 800;
        W1p[i] = (f16)(c < 784 ? W1[r * 784 + c] : 0.0f);
        return;
    }
    i -= 409600;
    if (i < 131072) { W2f[i] = (f16)W2[i]; return; }
    i -= 131072;
    if (i < 32768) { W3f[i] = (f16)W3[i]; return; }
    i -= 32768;
    if (i < 8192) { W4f[i] = (f16)W4[i]; return; }
    i -= 8192;
    if (i < 2048) { W5f[i] = (f16)W5[i]; return; }
    i -= 2048;
    if (i < 512) {
        int r = i >> 5, c = i & 31;
        W6p[i] = (f16)(r < 10 ? W6[r * 32 + c] : 0.0f);
        return;
    }
    i -= 512;
    if (i < 4096) { Wrf[i] = (f16)Wr[i]; return; }
}

// ---------------- xcvt: X fp32 [B][784] -> X16 fp16 [B][800] (K-padded) ----
__global__ __launch_bounds__(256)
void k_xcvt(const float* __restrict__ X, f16* __restrict__ X16) {
    const size_t t = (size_t)blockIdx.x * 256 + threadIdx.x; // B*200 threads
    const size_t row = t / 200;
    const int c4 = (int)(t - row * 200) * 4;
    f16x4 v = {0, 0, 0, 0};
    if (c4 < 784) {
        const float4 f = *(const float4*)(X + row * 784 + c4);
        v[0] = (f16)f.x; v[1] = (f16)f.y; v[2] = (f16)f.z; v[3] = (f16)f.w;
    }
    *(f16x4*)(X16 + row * 800 + c4) = v;
}

// ---------------- GEMM1: H1 = gelu(X16 @ W1p^T + b1), 128x256 tile --------
// KW = A/B row stride (f16), NOUT = C row stride, KT = K/32 iters
__global__ __launch_bounds__(256, 2)
void k_gemm1(const f16* __restrict__ A, const f16* __restrict__ Bw,
             const float* __restrict__ bias, f16* __restrict__ C) {
    __shared__ f16 As[128 * 32];
    __shared__ f16 Bs[256 * 32];
    const int tid = threadIdx.x;
    const int wave = tid >> 6, lane = tid & 63;
    const int nt = blockIdx.x & 1;           // 512 / 256
    const size_t mt = blockIdx.x >> 1;
    const size_t row0 = mt * 128;
    const int col0 = nt * 256;
    const int am = lane & 15, akg = lane >> 4, ak = akg * 8;
    const int wm = (wave & 1) * 64, wn = (wave >> 1) * 128;
    const f32x4 zero4 = {0.f, 0.f, 0.f, 0.f};
    f32x4 acc[4][8];
#pragma unroll
    for (int i = 0; i < 4; ++i)
#pragma unroll
        for (int j = 0; j < 8; ++j) acc[i][j] = zero4;

    const int srow = lane >> 2;
    const int scol = (lane & 3) * 8;

    for (int kt = 0; kt < 25; ++kt) {
        const int kb = kt * 32;
#pragma unroll
        for (int i = 0; i < 2; ++i) {
            const int inst = wave * 2 + i;
            load_lds16(A + (row0 + inst * 16 + srow) * 800 + kb + scol, &As[inst * 512]);
        }
#pragma unroll
        for (int i = 0; i < 4; ++i) {
            const int inst = wave * 4 + i;
            load_lds16(Bw + (size_t)(col0 + inst * 16 + srow) * 800 + kb + scol, &Bs[inst * 512]);
        }
        __syncthreads();
        f16x8 af[4], bf[8];
#pragma unroll
        for (int i = 0; i < 4; ++i) af[i] = *(const f16x8*)&As[(wm + i * 16 + am) * 32 + ak];
#pragma unroll
        for (int j = 0; j < 8; ++j) bf[j] = *(const f16x8*)&Bs[(wn + j * 16 + am) * 32 + ak];
#pragma unroll
        for (int i = 0; i < 4; ++i)
#pragma unroll
            for (int j = 0; j < 8; ++j)
                acc[i][j] = MFMA16(af[i], bf[j], acc[i][j]);
        __syncthreads();
    }
    const int cr = akg * 4;
#pragma unroll
    for (int j = 0; j < 8; ++j) {
        const int col = col0 + wn + j * 16 + am;
        const float b = bias[col];
#pragma unroll
        for (int i = 0; i < 4; ++i) {
            const size_t row = row0 + wm + i * 16 + cr;
#pragma unroll
            for (int r = 0; r < 4; ++r)
                C[(row + r) * 512 + col] = (f16)gelu_f(acc[i][j][r] + b);
        }
    }
}

// ---------------- GEMM2: MID = gelu(H1 @ W2^T + b2), 128x256 (full N) -----
__global__ __launch_bounds__(256, 2)
void k_gemm2(const f16* __restrict__ A, const f16* __restrict__ Bw,
             const float* __restrict__ bias, f16* __restrict__ C) {
    __shared__ f16 As[128 * 32];
    __shared__ f16 Bs[256 * 32];
    const int tid = threadIdx.x;
    const int wave = tid >> 6, lane = tid & 63;
    const size_t row0 = (size_t)blockIdx.x * 128;
    const int am = lane & 15, akg = lane >> 4, ak = akg * 8;
    const int wm = (wave & 1) * 64, wn = (wave >> 1) * 128;
    const f32x4 zero4 = {0.f, 0.f, 0.f, 0.f};
    f32x4 acc[4][8];
#pragma unroll
    for (int i = 0; i < 4; ++i)
#pragma unroll
        for (int j = 0; j < 8; ++j) acc[i][j] = zero4;

    const int srow = lane >> 2;
    const int scol = (lane & 3) * 8;

    for (int kt = 0; kt < 16; ++kt) {
        const int kb = kt * 32;
#pragma unroll
        for (int i = 0; i < 2; ++i) {
            const int inst = wave * 2 + i;
            load_lds16(A + (row0 + inst * 16 + srow) * 512 + kb + scol, &As[inst * 512]);
        }
#pragma unroll
        for (int i = 0; i < 4; ++i) {
            const int inst = wave * 4 + i;
            load_lds16(Bw + (size_t)(inst * 16 + srow) * 512 + kb + scol, &Bs[inst * 512]);
        }
        __syncthreads();
        f16x8 af[4], bf[8];
#pragma unroll
        for (int i = 0; i < 4; ++i) af[i] = *(const f16x8*)&As[(wm + i * 16 + am) * 32 + ak];
#pragma unroll
        for (int j = 0; j < 8; ++j) bf[j] = *(const f16x8*)&Bs[(wn + j * 16 + am) * 32 + ak];
#pragma unroll
        for (int i = 0; i < 4; ++i)
#pragma unroll
            for (int j = 0; j < 8; ++j)
                acc[i][j] = MFMA16(af[i], bf[j], acc[i][j]);
        __syncthreads();
    }
    const int cr = akg * 4;
#pragma unroll
    for (int j = 0; j < 8; ++j) {
        const int col = wn + j * 16 + am;
        const float b = bias[col];
#pragma unroll
        for (int i = 0; i < 4; ++i) {
            const size_t row = row0 + wm + i * 16 + cr;
#pragma unroll
            for (int r = 0; r < 4; ++r)
                C[(row + r) * 256 + col] = (f16)gelu_f(acc[i][j][r] + b);
        }
    }
}

// ---------------- fused tail: router + grouped fc3 + L4 + L5 + L6 ----------
__global__ __launch_bounds__(256, 2)
void k_tail(const f16* __restrict__ MID,
            const f16* __restrict__ W3f, const float* __restrict__ b3,
            const f16* __restrict__ W4f, const float* __restrict__ b4,
            const f16* __restrict__ W5f, const float* __restrict__ b5,
            const f16* __restrict__ W6p, const float* __restrict__ b6v,
            const f16* __restrict__ Wrf, const float* __restrict__ brv,
            float* __restrict__ OUT) {
    __shared__ f16 s_mid[64 * 264];     // mid_in tile, stride 264 (+8 pad)
    __shared__ float s_pw[64 * 20];     // 16 pathway weights + 4 group-sums
    __shared__ f16 s_mo[64 * 136];      // mid_out, stride 136
    __shared__ f16 s_h4[64 * 72];       // h4, stride 72
    __shared__ f16 s_h5[64 * 40];       // h5, stride 40
    const int tid = threadIdx.x, wave = tid >> 6, lane = tid & 63;
    const size_t r0 = (size_t)blockIdx.x * 64;
    const int am = lane & 15, akg = lane >> 4, ak = akg * 8;
    const int wr = wave * 16;
    const int crow = wr + akg * 4;
    const f32x4 zero4 = {0.f, 0.f, 0.f, 0.f};

    // phase 1: stage mid_in [64][256] -> LDS
    {
        const int row = tid >> 2, seg = (tid & 3) * 64;
        const f16* src = MID + (r0 + row) * 256 + seg;
        f16* dst = s_mid + row * 264 + seg;
#pragma unroll
        for (int c = 0; c < 8; ++c)
            *(f16x8*)(dst + c * 8) = *(const f16x8*)(src + c * 8);
    }
    __syncthreads();

    // phase 2: router logits + softmax across 16 lanes
    {
        f32x4 lacc = zero4;
#pragma unroll
        for (int ks = 0; ks < 8; ++ks) {
            f16x8 a = *(const f16x8*)(s_mid + (wr + am) * 264 + ks * 32 + ak);
            f16x8 b = *(const f16x8*)(Wrf + am * 256 + ks * 32 + ak);
            lacc = MFMA16(a, b, lacc);
        }
        const float brn = brv[am];
#pragma unroll
        for (int r = 0; r < 4; ++r) {
            float l = lacc[r] + brn;
            float mx = l;
#pragma unroll
            for (int m = 1; m <= 8; m <<= 1) mx = fmaxf(mx, __shfl_xor(mx, m));
            const float e = __expf(l - mx);
            float s = e;
#pragma unroll
            for (int m = 1; m <= 8; m <<= 1) s += __shfl_xor(s, m);
            const float p = e / s;
            float sg = p;
            sg += __shfl_xor(sg, 4);
            sg += __shfl_xor(sg, 8);
            s_pw[(crow + r) * 20 + am] = p;
            if (am < 4) s_pw[(crow + r) * 20 + 16 + am] = sg;
        }
    }
    __syncthreads();

    // phase 3: grouped fc3 + pathway-weighted combine + gelu -> s_mo
    {
        f16x8 a3[4][2];
#pragma unroll
        for (int g = 0; g < 4; ++g)
#pragma unroll
            for (int kh = 0; kh < 2; ++kh)
                a3[g][kh] = *(const f16x8*)(s_mid + (wr + am) * 264 + g * 64 + kh * 32 + ak);
#pragma unroll
        for (int o = 0; o < 4; ++o) {
            float pwv[4][4], sgl[4];
#pragma unroll
            for (int r = 0; r < 4; ++r) {
                sgl[r] = s_pw[(crow + r) * 20 + 16 + o];
#pragma unroll
                for (int g = 0; g < 4; ++g)
                    pwv[g][r] = s_pw[(crow + r) * 20 + g * 4 + o];
            }
#pragma unroll
            for (int ctl = 0; ctl < 2; ++ctl) {
                const int ct = o * 2 + ctl;
                const int col = ct * 16 + am;
                const float bias = b3[col];
                f32x4 oacc;
#pragma unroll
                for (int r = 0; r < 4; ++r) oacc[r] = bias * sgl[r];
#pragma unroll
                for (int g = 0; g < 4; ++g) {
                    f32x4 t = zero4;
                    t = MFMA16(a3[g][0], *(const f16x8*)(W3f + (size_t)col * 256 + g * 64 + ak), t);
                    t = MFMA16(a3[g][1], *(const f16x8*)(W3f + (size_t)col * 256 + g * 64 + 32 + ak), t);
#pragma unroll
                    for (int r = 0; r < 4; ++r) oacc[r] += pwv[g][r] * t[r];
                }
#pragma unroll
                for (int r = 0; r < 4; ++r)
                    s_mo[(crow + r) * 136 + col] = (f16)gelu_f(oacc[r]);
            }
        }
    }
    __syncthreads();

    // phase 4: L4
    {
        f16x8 a4[4];
#pragma unroll
        for (int ks = 0; ks < 4; ++ks)
            a4[ks] = *(const f16x8*)(s_mo + (wr + am) * 136 + ks * 32 + ak);
#pragma unroll
        for (int ct = 0; ct < 4; ++ct) {
            const int col = ct * 16 + am;
            f32x4 acc = zero4;
#pragma unroll
            for (int ks = 0; ks < 4; ++ks)
                acc = MFMA16(a4[ks], *(const f16x8*)(W4f + (size_t)col * 128 + ks * 32 + ak), acc);
            const float bias = b4[col];
#pragma unroll
            for (int r = 0; r < 4; ++r)
                s_h4[(crow + r) * 72 + col] = (f16)gelu_f(acc[r] + bias);
        }
    }
    __syncthreads();

    // phase 5: L5
    {
        f16x8 a5[2];
#pragma unroll
        for (int ks = 0; ks < 2; ++ks)
            a5[ks] = *(const f16x8*)(s_h4 + (wr + am) * 72 + ks * 32 + ak);
#pragma unroll
        for (int ct = 0; ct < 2; ++ct) {
            const int col = ct * 16 + am;
            f32x4 acc = zero4;
#pragma unroll
            for (int ks = 0; ks < 2; ++ks)
                acc = MFMA16(a5[ks], *(const f16x8*)(W5f + (size_t)col * 64 + ks * 32 + ak), acc);
            const float bias = b5[col];
#pragma unroll
            for (int r = 0; r < 4; ++r)
                s_h5[(crow + r) * 40 + col] = (f16)gelu_f(acc[r] + bias);
        }
    }
    __syncthreads();

    // phase 6: L6
    {
        f16x8 a6 = *(const f16x8*)(s_h5 + (wr + am) * 40 + ak);
        f16x8 bw = *(const f16x8*)(W6p + am * 32 + ak);
        f32x4 acc = MFMA16(a6, bw, zero4);
        if (am < 10) {
            const float bb = b6v[am];
#pragma unroll
            for (int r = 0; r < 4; ++r)
                OUT[(r0 + crow + r) * 10 + am] = acc[r] + bb;
        }
    }
}

extern "C" void kernel_launch(void* const* d_in, const int* in_sizes, int n_in,
                              void* d_out, int out_size, void* d_ws, size_t ws_size,
                              hipStream_t stream) {
    const float* x  = (const float*)d_in[0];
    const float* W1 = (const float*)d_in[1];
    const float* b1 = (const float*)d_in[2];
    const float* W2 = (const float*)d_in[3];
    const float* b2 = (const float*)d_in[4];
    const float* W3 = (const float*)d_in[5];
    const float* b3 = (const float*)d_in[6];
    const float* W4 = (const float*)d_in[7];
    const float* b4 = (const float*)d_in[8];
    const float* W5 = (const float*)d_in[9];
    const float* b5 = (const float*)d_in[10];
    const float* W6 = (const float*)d_in[11];
    const float* b6 = (const float*)d_in[12];
    const float* Wr = (const float*)d_in[13];
    const float* br = (const float*)d_in[14];
    float* out = (float*)d_out;

    const int M = in_sizes[0] / 784;    // 131072

    char* ws = (char*)d_ws;
    f16* W1p = (f16*)ws; ws += 512 * 800 * 2;
    f16* W2f = (f16*)ws; ws += 256 * 512 * 2;
    f16* W3f = (f16*)ws; ws += 128 * 256 * 2;
    f16* W4f = (f16*)ws; ws += 64 * 128 * 2;
    f16* W5f = (f16*)ws; ws += 32 * 64 * 2;
    f16* W6p = (f16*)ws; ws += 16 * 32 * 2;
    f16* Wrf = (f16*)ws; ws += 16 * 256 * 2;
    // X16 [M][800] fp16; MIDB aliases it (X16 dead once gemm1 completes)
    f16* X16 = (f16*)ws;
    f16* MIDB = (f16*)ws; ws += (size_t)M * 800 * 2;
    f16* H1  = (f16*)ws; ws += (size_t)M * 512 * 2;

    k_prep<<<2298, 256, 0, stream>>>(W1, W2, W3, W4, W5, W6, Wr,
                                     W1p, W2f, W3f, W4f, W5f, W6p, Wrf);
    k_xcvt<<<(M * 200) / 256, 256, 0, stream>>>(x, X16);
    k_gemm1<<<(M / 128) * 2, 256, 0, stream>>>(X16, W1p, b1, H1);
    k_gemm2<<<M / 128, 256, 0, stream>>>(H1, W2f, b2, MIDB);
    k_tail<<<M / 64, 256, 0, stream>>>(MIDB, W3f, b3, W4f, b4, W5f, b5,
                                       W6p, b6, Wrf, br, out);
}

// Round 4
// 906.453 us; speedup vs baseline: 1.2414x; 1.0870x over previous
//
#include <hip/hip_runtime.h>
#include <cstdint>

typedef _Float16 f16;
typedef _Float16 f16x4 __attribute__((ext_vector_type(4)));
typedef _Float16 f16x8 __attribute__((ext_vector_type(8)));
typedef float f32x4 __attribute__((ext_vector_type(4)));

#define MFMA16(a, b, c) __builtin_amdgcn_mfma_f32_16x16x32_f16((a), (b), (c), 0, 0, 0)

// fast gelu: 0.5x(1+tanh(0.79788456(x+0.044715x^3))) == x*sigmoid(1.59576912x+0.07135482x^3)
__device__ __forceinline__ float gelu_f(float x) {
    const float u = x * (1.5957691216f + 0.0713548163f * x * x);
    return x * __builtin_amdgcn_rcpf(1.0f + __expf(-u));
}

__device__ __forceinline__ void load_lds16(const void* g, void* l) {
    __builtin_amdgcn_global_load_lds(
        (const __attribute__((address_space(1))) void*)(uintptr_t)g,
        (__attribute__((address_space(3))) void*)(uint32_t)(uintptr_t)l,
        16, 0, 0);
}

// ---------------- prep: fp32 weights -> fp16 (with padding) ----------------
// W1p [512][832] (K pad 784->832, zeros), W2f[256][512], W3f[128][256],
// W4f[64][128], W5f[32][64], W6p[16][32] (rows 10..15 zero), Wrf[16][256]
__global__ void k_prep(const float* __restrict__ W1, const float* __restrict__ W2,
                       const float* __restrict__ W3, const float* __restrict__ W4,
                       const float* __restrict__ W5, const float* __restrict__ W6,
                       const float* __restrict__ Wr,
                       f16* __restrict__ W1p, f16* __restrict__ W2f, f16* __restrict__ W3f,
                       f16* __restrict__ W4f, f16* __restrict__ W5f, f16* __restrict__ W6p,
                       f16* __restrict__ Wrf) {
    int i = blockIdx.x * 256 + threadIdx.x;
    if (i < 425984) {
        int r = i / 832, c = i - r * 832;
        W1p[i] = (f16)(c < 784 ? W1[r * 784 + c] : 0.0f);
        return;
    }
    i -= 425984;
    if (i < 131072) { W2f[i] = (f16)W2[i]; return; }
    i -= 131072;
    if (i < 32768) { W3f[i] = (f16)W3[i]; return; }
    i -= 32768;
    if (i < 8192) { W4f[i] = (f16)W4[i]; return; }
    i -= 8192;
    if (i < 2048) { W5f[i] = (f16)W5[i]; return; }
    i -= 2048;
    if (i < 512) {
        int r = i >> 5, c = i & 31;
        W6p[i] = (f16)(r < 10 ? W6[r * 32 + c] : 0.0f);
        return;
    }
    i -= 512;
    if (i < 4096) { Wrf[i] = (f16)Wr[i]; return; }
}

// ---------------- xcvt: X fp32 [B][784] -> X16 fp16 [B][832] (K-padded) ----
__global__ __launch_bounds__(256)
void k_xcvt(const float* __restrict__ X, f16* __restrict__ X16) {
    const size_t t = (size_t)blockIdx.x * 256 + threadIdx.x; // B*208 threads
    const size_t row = t / 208;
    const int c4 = (int)(t - row * 208) * 4;
    f16x4 v = {0, 0, 0, 0};
    if (c4 < 784) {
        const float4 f = *(const float4*)(X + row * 784 + c4);
        v[0] = (f16)f.x; v[1] = (f16)f.y; v[2] = (f16)f.z; v[3] = (f16)f.w;
    }
    *(f16x4*)(X16 + row * 832 + c4) = v;
}

// ---------------- GEMM1: H1 = gelu(X16 @ W1p^T + b1), 128x256, BK=64 ------
// LDS: two stride-32 panels per operand. Swapped-operand MFMA -> transposed
// C fragment: lane holds 4 consecutive cols of one row -> 8B packed stores.
__global__ __launch_bounds__(256, 2)
void k_gemm1(const f16* __restrict__ A, const f16* __restrict__ Bw,
             const float* __restrict__ bias, f16* __restrict__ C) {
    __shared__ f16 As[2 * 128 * 32];
    __shared__ f16 Bs[2 * 256 * 32];
    const int tid = threadIdx.x;
    const int wave = tid >> 6, lane = tid & 63;
    const int nt = blockIdx.x & 1;           // 512 / 256
    const size_t mt = blockIdx.x >> 1;
    const size_t row0 = mt * 128;
    const int col0 = nt * 256;
    const int am = lane & 15, akg = lane >> 4, ak = akg * 8;
    const int wm = (wave & 1) * 64, wn = (wave >> 1) * 128;
    const f32x4 zero4 = {0.f, 0.f, 0.f, 0.f};
    f32x4 acc[4][8];
#pragma unroll
    for (int i = 0; i < 4; ++i)
#pragma unroll
        for (int j = 0; j < 8; ++j) acc[i][j] = zero4;

    const int srow = lane >> 2;
    const int scol = (lane & 3) * 8;

    for (int kt = 0; kt < 13; ++kt) {
        const int kb = kt * 64;
#pragma unroll
        for (int p = 0; p < 2; ++p) {
#pragma unroll
            for (int i = 0; i < 2; ++i) {
                const int inst = wave * 2 + i;
                load_lds16(A + (row0 + inst * 16 + srow) * 832 + kb + p * 32 + scol,
                           &As[p * 4096 + inst * 512]);
            }
#pragma unroll
            for (int i = 0; i < 4; ++i) {
                const int inst = wave * 4 + i;
                load_lds16(Bw + (size_t)(col0 + inst * 16 + srow) * 832 + kb + p * 32 + scol,
                           &Bs[p * 8192 + inst * 512]);
            }
        }
        __syncthreads();
#pragma unroll
        for (int ks = 0; ks < 2; ++ks) {
            f16x8 af[4], bf[8];
#pragma unroll
            for (int i = 0; i < 4; ++i)
                af[i] = *(const f16x8*)&As[ks * 4096 + (wm + i * 16 + am) * 32 + ak];
#pragma unroll
            for (int j = 0; j < 8; ++j)
                bf[j] = *(const f16x8*)&Bs[ks * 8192 + (wn + j * 16 + am) * 32 + ak];
#pragma unroll
            for (int i = 0; i < 4; ++i)
#pragma unroll
                for (int j = 0; j < 8; ++j)
                    acc[i][j] = MFMA16(bf[j], af[i], acc[i][j]);  // swapped -> C^T frag
        }
        __syncthreads();
    }
    // epilogue: lane holds rows (am) x 4 consecutive cols (akg*4+r)
    const int cc = akg * 4;
#pragma unroll
    for (int i = 0; i < 4; ++i) {
        const size_t row = row0 + wm + i * 16 + am;
#pragma unroll
        for (int j = 0; j < 8; ++j) {
            const int col = col0 + wn + j * 16 + cc;
            const float4 b4 = *(const float4*)(bias + col);
            f16x4 v;
            v[0] = (f16)gelu_f(acc[i][j][0] + b4.x);
            v[1] = (f16)gelu_f(acc[i][j][1] + b4.y);
            v[2] = (f16)gelu_f(acc[i][j][2] + b4.z);
            v[3] = (f16)gelu_f(acc[i][j][3] + b4.w);
            *(f16x4*)(C + row * 512 + col) = v;
        }
    }
}

// ---------------- GEMM2: MID = gelu(H1 @ W2^T + b2), 128x256, BK=64 -------
__global__ __launch_bounds__(256, 2)
void k_gemm2(const f16* __restrict__ A, const f16* __restrict__ Bw,
             const float* __restrict__ bias, f16* __restrict__ C) {
    __shared__ f16 As[2 * 128 * 32];
    __shared__ f16 Bs[2 * 256 * 32];
    const int tid = threadIdx.x;
    const int wave = tid >> 6, lane = tid & 63;
    const size_t row0 = (size_t)blockIdx.x * 128;
    const int am = lane & 15, akg = lane >> 4, ak = akg * 8;
    const int wm = (wave & 1) * 64, wn = (wave >> 1) * 128;
    const f32x4 zero4 = {0.f, 0.f, 0.f, 0.f};
    f32x4 acc[4][8];
#pragma unroll
    for (int i = 0; i < 4; ++i)
#pragma unroll
        for (int j = 0; j < 8; ++j) acc[i][j] = zero4;

    const int srow = lane >> 2;
    const int scol = (lane & 3) * 8;

    for (int kt = 0; kt < 8; ++kt) {
        const int kb = kt * 64;
#pragma unroll
        for (int p = 0; p < 2; ++p) {
#pragma unroll
            for (int i = 0; i < 2; ++i) {
                const int inst = wave * 2 + i;
                load_lds16(A + (row0 + inst * 16 + srow) * 512 + kb + p * 32 + scol,
                           &As[p * 4096 + inst * 512]);
            }
#pragma unroll
            for (int i = 0; i < 4; ++i) {
                const int inst = wave * 4 + i;
                load_lds16(Bw + (size_t)(inst * 16 + srow) * 512 + kb + p * 32 + scol,
                           &Bs[p * 8192 + inst * 512]);
            }
        }
        __syncthreads();
#pragma unroll
        for (int ks = 0; ks < 2; ++ks) {
            f16x8 af[4], bf[8];
#pragma unroll
            for (int i = 0; i < 4; ++i)
                af[i] = *(const f16x8*)&As[ks * 4096 + (wm + i * 16 + am) * 32 + ak];
#pragma unroll
            for (int j = 0; j < 8; ++j)
                bf[j] = *(const f16x8*)&Bs[ks * 8192 + (wn + j * 16 + am) * 32 + ak];
#pragma unroll
            for (int i = 0; i < 4; ++i)
#pragma unroll
                for (int j = 0; j < 8; ++j)
                    acc[i][j] = MFMA16(bf[j], af[i], acc[i][j]);
        }
        __syncthreads();
    }
    const int cc = akg * 4;
#pragma unroll
    for (int i = 0; i < 4; ++i) {
        const size_t row = row0 + wm + i * 16 + am;
#pragma unroll
        for (int j = 0; j < 8; ++j) {
            const int col = wn + j * 16 + cc;
            const float4 b4 = *(const float4*)(bias + col);
            f16x4 v;
            v[0] = (f16)gelu_f(acc[i][j][0] + b4.x);
            v[1] = (f16)gelu_f(acc[i][j][1] + b4.y);
            v[2] = (f16)gelu_f(acc[i][j][2] + b4.z);
            v[3] = (f16)gelu_f(acc[i][j][3] + b4.w);
            *(f16x4*)(C + row * 256 + col) = v;
        }
    }
}

// ---------------- fused tail: router + grouped fc3 + L4 + L5 + L6 ----------
__global__ __launch_bounds__(256, 2)
void k_tail(const f16* __restrict__ MID,
            const f16* __restrict__ W3f, const float* __restrict__ b3,
            const f16* __restrict__ W4f, const float* __restrict__ b4,
            const f16* __restrict__ W5f, const float* __restrict__ b5,
            const f16* __restrict__ W6p, const float* __restrict__ b6v,
            const f16* __restrict__ Wrf, const float* __restrict__ brv,
            float* __restrict__ OUT) {
    __shared__ f16 s_mid[64 * 264];     // mid_in tile, stride 264 (+8 pad)
    __shared__ float s_pw[64 * 20];     // 16 pathway weights + 4 group-sums
    __shared__ f16 s_mo[64 * 136];      // mid_out, stride 136
    __shared__ f16 s_h4[64 * 72];       // h4, stride 72
    __shared__ f16 s_h5[64 * 40];       // h5, stride 40
    const int tid = threadIdx.x, wave = tid >> 6, lane = tid & 63;
    const size_t r0 = (size_t)blockIdx.x * 64;
    const int am = lane & 15, akg = lane >> 4, ak = akg * 8;
    const int wr = wave * 16;
    const int crow = wr + akg * 4;
    const f32x4 zero4 = {0.f, 0.f, 0.f, 0.f};

    // phase 1: stage mid_in [64][256] -> LDS
    {
        const int row = tid >> 2, seg = (tid & 3) * 64;
        const f16* src = MID + (r0 + row) * 256 + seg;
        f16* dst = s_mid + row * 264 + seg;
#pragma unroll
        for (int c = 0; c < 8; ++c)
            *(f16x8*)(dst + c * 8) = *(const f16x8*)(src + c * 8);
    }
    __syncthreads();

    // phase 2: router logits + softmax across 16 lanes
    {
        f32x4 lacc = zero4;
#pragma unroll
        for (int ks = 0; ks < 8; ++ks) {
            f16x8 a = *(const f16x8*)(s_mid + (wr + am) * 264 + ks * 32 + ak);
            f16x8 b = *(const f16x8*)(Wrf + am * 256 + ks * 32 + ak);
            lacc = MFMA16(a, b, lacc);
        }
        const float brn = brv[am];
#pragma unroll
        for (int r = 0; r < 4; ++r) {
            float l = lacc[r] + brn;
            float mx = l;
#pragma unroll
            for (int m = 1; m <= 8; m <<= 1) mx = fmaxf(mx, __shfl_xor(mx, m));
            const float e = __expf(l - mx);
            float s = e;
#pragma unroll
            for (int m = 1; m <= 8; m <<= 1) s += __shfl_xor(s, m);
            const float p = e / s;
            float sg = p;
            sg += __shfl_xor(sg, 4);
            sg += __shfl_xor(sg, 8);
            s_pw[(crow + r) * 20 + am] = p;
            if (am < 4) s_pw[(crow + r) * 20 + 16 + am] = sg;
        }
    }
    __syncthreads();

    // phase 3: grouped fc3 + pathway-weighted combine + gelu -> s_mo
    {
        f16x8 a3[4][2];
#pragma unroll
        for (int g = 0; g < 4; ++g)
#pragma unroll
            for (int kh = 0; kh < 2; ++kh)
                a3[g][kh] = *(const f16x8*)(s_mid + (wr + am) * 264 + g * 64 + kh * 32 + ak);
#pragma unroll
        for (int o = 0; o < 4; ++o) {
            float pwv[4][4], sgl[4];
#pragma unroll
            for (int r = 0; r < 4; ++r) {
                sgl[r] = s_pw[(crow + r) * 20 + 16 + o];
#pragma unroll
                for (int g = 0; g < 4; ++g)
                    pwv[g][r] = s_pw[(crow + r) * 20 + g * 4 + o];
            }
#pragma unroll
            for (int ctl = 0; ctl < 2; ++ctl) {
                const int ct = o * 2 + ctl;
                const int col = ct * 16 + am;
                const float bias = b3[col];
                f32x4 oacc;
#pragma unroll
                for (int r = 0; r < 4; ++r) oacc[r] = bias * sgl[r];
#pragma unroll
                for (int g = 0; g < 4; ++g) {
                    f32x4 t = zero4;
                    t = MFMA16(a3[g][0], *(const f16x8*)(W3f + (size_t)col * 256 + g * 64 + ak), t);
                    t = MFMA16(a3[g][1], *(const f16x8*)(W3f + (size_t)col * 256 + g * 64 + 32 + ak), t);
#pragma unroll
                    for (int r = 0; r < 4; ++r) oacc[r] += pwv[g][r] * t[r];
                }
#pragma unroll
                for (int r = 0; r < 4; ++r)
                    s_mo[(crow + r) * 136 + col] = (f16)gelu_f(oacc[r]);
            }
        }
    }
    __syncthreads();

    // phase 4: L4
    {
        f16x8 a4[4];
#pragma unroll
        for (int ks = 0; ks < 4; ++ks)
            a4[ks] = *(const f16x8*)(s_mo + (wr + am) * 136 + ks * 32 + ak);
#pragma unroll
        for (int ct = 0; ct < 4; ++ct) {
            const int col = ct * 16 + am;
            f32x4 acc = zero4;
#pragma unroll
            for (int ks = 0; ks < 4; ++ks)
                acc = MFMA16(a4[ks], *(const f16x8*)(W4f + (size_t)col * 128 + ks * 32 + ak), acc);
            const float bias = b4[col];
#pragma unroll
            for (int r = 0; r < 4; ++r)
                s_h4[(crow + r) * 72 + col] = (f16)gelu_f(acc[r] + bias);
        }
    }
    __syncthreads();

    // phase 5: L5
    {
        f16x8 a5[2];
#pragma unroll
        for (int ks = 0; ks < 2; ++ks)
            a5[ks] = *(const f16x8*)(s_h4 + (wr + am) * 72 + ks * 32 + ak);
#pragma unroll
        for (int ct = 0; ct < 2; ++ct) {
            const int col = ct * 16 + am;
            f32x4 acc = zero4;
#pragma unroll
            for (int ks = 0; ks < 2; ++ks)
                acc = MFMA16(a5[ks], *(const f16x8*)(W5f + (size_t)col * 64 + ks * 32 + ak), acc);
            const float bias = b5[col];
#pragma unroll
            for (int r = 0; r < 4; ++r)
                s_h5[(crow + r) * 40 + col] = (f16)gelu_f(acc[r] + bias);
        }
    }
    __syncthreads();

    // phase 6: L6
    {
        f16x8 a6 = *(const f16x8*)(s_h5 + (wr + am) * 40 + ak);
        f16x8 bw = *(const f16x8*)(W6p + am * 32 + ak);
        f32x4 acc = MFMA16(a6, bw, zero4);
        if (am < 10) {
            const float bb = b6v[am];
#pragma unroll
            for (int r = 0; r < 4; ++r)
                OUT[(r0 + crow + r) * 10 + am] = acc[r] + bb;
        }
    }
}

extern "C" void kernel_launch(void* const* d_in, const int* in_sizes, int n_in,
                              void* d_out, int out_size, void* d_ws, size_t ws_size,
                              hipStream_t stream) {
    const float* x  = (const float*)d_in[0];
    const float* W1 = (const float*)d_in[1];
    const float* b1 = (const float*)d_in[2];
    const float* W2 = (const float*)d_in[3];
    const float* b2 = (const float*)d_in[4];
    const float* W3 = (const float*)d_in[5];
    const float* b3 = (const float*)d_in[6];
    const float* W4 = (const float*)d_in[7];
    const float* b4 = (const float*)d_in[8];
    const float* W5 = (const float*)d_in[9];
    const float* b5 = (const float*)d_in[10];
    const float* W6 = (const float*)d_in[11];
    const float* b6 = (const float*)d_in[12];
    const float* Wr = (const float*)d_in[13];
    const float* br = (const float*)d_in[14];
    float* out = (float*)d_out;

    const int M = in_sizes[0] / 784;    // 131072

    char* ws = (char*)d_ws;
    f16* W1p = (f16*)ws; ws += 512 * 832 * 2;
    f16* W2f = (f16*)ws; ws += 256 * 512 * 2;
    f16* W3f = (f16*)ws; ws += 128 * 256 * 2;
    f16* W4f = (f16*)ws; ws += 64 * 128 * 2;
    f16* W5f = (f16*)ws; ws += 32 * 64 * 2;
    f16* W6p = (f16*)ws; ws += 16 * 32 * 2;
    f16* Wrf = (f16*)ws; ws += 16 * 256 * 2;
    // X16 [M][832] fp16; MIDB aliases it (X16 dead once gemm1 completes)
    f16* X16 = (f16*)ws;
    f16* MIDB = (f16*)ws; ws += (size_t)M * 832 * 2;
    f16* H1  = (f16*)ws; ws += (size_t)M * 512 * 2;

    k_prep<<<2362, 256, 0, stream>>>(W1, W2, W3, W4, W5, W6, Wr,
                                     W1p, W2f, W3f, W4f, W5f, W6p, Wrf);
    k_xcvt<<<(M * 208) / 256, 256, 0, stream>>>(x, X16);
    k_gemm1<<<(M / 128) * 2, 256, 0, stream>>>(X16, W1p, b1, H1);
    k_gemm2<<<M / 128, 256, 0, stream>>>(H1, W2f, b2, MIDB);
    k_tail<<<M / 64, 256, 0, stream>>>(MIDB, W3f, b3, W4f, b4, W5f, b5,
                                       W6p, b6, Wrf, br, out);
}

// Round 5
// 883.527 us; speedup vs baseline: 1.2736x; 1.0259x over previous
//
#include <hip/hip_runtime.h>
#include <cstdint>

typedef _Float16 f16;
typedef _Float16 f16x4 __attribute__((ext_vector_type(4)));
typedef _Float16 f16x8 __attribute__((ext_vector_type(8)));
typedef float f32x4 __attribute__((ext_vector_type(4)));

#define MFMA16(a, b, c) __builtin_amdgcn_mfma_f32_16x16x32_f16((a), (b), (c), 0, 0, 0)

// fast gelu: x * sigmoid(1.59576912x + 0.07135482x^3)  (tanh-gelu identity)
__device__ __forceinline__ float gelu_f(float x) {
    const float u = x * (1.5957691216f + 0.0713548163f * x * x);
    return x * __builtin_amdgcn_rcpf(1.0f + __expf(-u));
}

__device__ __forceinline__ void load_lds16(const void* g, void* l) {
    __builtin_amdgcn_global_load_lds(
        (const __attribute__((address_space(1))) void*)(uintptr_t)g,
        (__attribute__((address_space(3))) void*)(uint32_t)(uintptr_t)l,
        16, 0, 0);
}

// ---------------- prep: fp32 weights -> fp16 (with padding) ----------------
// W1p [512][832] (K pad 784->832, zeros), W2f[256][512], W3f[128][256],
// W4f[64][128], W5f[32][64], W6p[16][32] (rows 10..15 zero), Wrf[16][256]
__global__ void k_prep(const float* __restrict__ W1, const float* __restrict__ W2,
                       const float* __restrict__ W3, const float* __restrict__ W4,
                       const float* __restrict__ W5, const float* __restrict__ W6,
                       const float* __restrict__ Wr,
                       f16* __restrict__ W1p, f16* __restrict__ W2f, f16* __restrict__ W3f,
                       f16* __restrict__ W4f, f16* __restrict__ W5f, f16* __restrict__ W6p,
                       f16* __restrict__ Wrf) {
    int i = blockIdx.x * 256 + threadIdx.x;
    if (i < 425984) {
        int r = i / 832, c = i - r * 832;
        W1p[i] = (f16)(c < 784 ? W1[r * 784 + c] : 0.0f);
        return;
    }
    i -= 425984;
    if (i < 131072) { W2f[i] = (f16)W2[i]; return; }
    i -= 131072;
    if (i < 32768) { W3f[i] = (f16)W3[i]; return; }
    i -= 32768;
    if (i < 8192) { W4f[i] = (f16)W4[i]; return; }
    i -= 8192;
    if (i < 2048) { W5f[i] = (f16)W5[i]; return; }
    i -= 2048;
    if (i < 512) {
        int r = i >> 5, c = i & 31;
        W6p[i] = (f16)(r < 10 ? W6[r * 32 + c] : 0.0f);
        return;
    }
    i -= 512;
    if (i < 4096) { Wrf[i] = (f16)Wr[i]; return; }
}

// ---------------- GEMM1: H1 = gelu(X @ W1p^T + b1) ------------------------
// A: fp32 X, loaded DIRECTLY into fragments (per-lane float4 x2 + cvt) — no
// LDS, no barrier dep, each element fetched once/block, coalesced via akg.
// B: f16 W1p[512][832] via global_load_lds (stride 1664 B, 16B-aligned).
// Swapped-operand MFMA -> C^T fragment -> packed 8B stores.
__global__ __launch_bounds__(256, 2)
void k_gemm1(const float* __restrict__ A, const f16* __restrict__ Bw,
             const float* __restrict__ bias, f16* __restrict__ C) {
    __shared__ f16 Bs[2 * 256 * 32];
    const int tid = threadIdx.x;
    const int wave = tid >> 6, lane = tid & 63;
    const int nt = blockIdx.x & 1;           // 512 / 256
    const size_t mt = blockIdx.x >> 1;
    const size_t row0 = mt * 128;
    const int col0 = nt * 256;
    const int am = lane & 15, akg = lane >> 4, ak = akg * 8;
    const int wm = (wave & 1) * 64, wn = (wave >> 1) * 128;
    const f32x4 zero4 = {0.f, 0.f, 0.f, 0.f};
    const f16x8 zero8 = {0, 0, 0, 0, 0, 0, 0, 0};
    f32x4 acc[4][8];
#pragma unroll
    for (int i = 0; i < 4; ++i)
#pragma unroll
        for (int j = 0; j < 8; ++j) acc[i][j] = zero4;

    const int srow = lane >> 2;
    const int scol = (lane & 3) * 8;

    for (int kt = 0; kt < 13; ++kt) {
        const int kb = kt * 64;
        // B tile async: 2 panels of 256x32
#pragma unroll
        for (int p = 0; p < 2; ++p) {
#pragma unroll
            for (int i = 0; i < 4; ++i) {
                const int inst = wave * 4 + i;
                load_lds16(Bw + (size_t)(col0 + inst * 16 + srow) * 832 + kb + p * 32 + scol,
                           &Bs[p * 8192 + inst * 512]);
            }
        }
        // A fragments direct from global fp32 (predicated K-tail; W1p zeros
        // beyond col 783 kill any A garbage we'd otherwise multiply)
        f16x8 af[2][4];
#pragma unroll
        for (int ks = 0; ks < 2; ++ks) {
#pragma unroll
            for (int i = 0; i < 4; ++i) {
                const int c = kb + ks * 32 + ak;
                if (c < 784) {
                    const float* p = A + (row0 + wm + i * 16 + am) * 784 + c;
                    const float4 lo = *(const float4*)p;
                    const float4 hi = *(const float4*)(p + 4);
                    f16x8 v;
                    v[0] = (f16)lo.x; v[1] = (f16)lo.y; v[2] = (f16)lo.z; v[3] = (f16)lo.w;
                    v[4] = (f16)hi.x; v[5] = (f16)hi.y; v[6] = (f16)hi.z; v[7] = (f16)hi.w;
                    af[ks][i] = v;
                } else {
                    af[ks][i] = zero8;
                }
            }
        }
        __syncthreads();
#pragma unroll
        for (int ks = 0; ks < 2; ++ks) {
            f16x8 bf[8];
#pragma unroll
            for (int j = 0; j < 8; ++j)
                bf[j] = *(const f16x8*)&Bs[ks * 8192 + (wn + j * 16 + am) * 32 + ak];
#pragma unroll
            for (int i = 0; i < 4; ++i)
#pragma unroll
                for (int j = 0; j < 8; ++j)
                    acc[i][j] = MFMA16(bf[j], af[ks][i], acc[i][j]);  // C^T frag
        }
        __syncthreads();
    }
    // epilogue: lane holds row (am-based) x 4 consecutive cols
    const int cc = akg * 4;
#pragma unroll
    for (int i = 0; i < 4; ++i) {
        const size_t row = row0 + wm + i * 16 + am;
#pragma unroll
        for (int j = 0; j < 8; ++j) {
            const int col = col0 + wn + j * 16 + cc;
            const float4 b4 = *(const float4*)(bias + col);
            f16x4 v;
            v[0] = (f16)gelu_f(acc[i][j][0] + b4.x);
            v[1] = (f16)gelu_f(acc[i][j][1] + b4.y);
            v[2] = (f16)gelu_f(acc[i][j][2] + b4.z);
            v[3] = (f16)gelu_f(acc[i][j][3] + b4.w);
            *(f16x4*)(C + row * 512 + col) = v;
        }
    }
}

// ---------------- GEMM2: MID = gelu(H1 @ W2^T + b2), 128x256, BK=64 -------
__global__ __launch_bounds__(256, 2)
void k_gemm2(const f16* __restrict__ A, const f16* __restrict__ Bw,
             const float* __restrict__ bias, f16* __restrict__ C) {
    __shared__ f16 As[2 * 128 * 32];
    __shared__ f16 Bs[2 * 256 * 32];
    const int tid = threadIdx.x;
    const int wave = tid >> 6, lane = tid & 63;
    const size_t row0 = (size_t)blockIdx.x * 128;
    const int am = lane & 15, akg = lane >> 4, ak = akg * 8;
    const int wm = (wave & 1) * 64, wn = (wave >> 1) * 128;
    const f32x4 zero4 = {0.f, 0.f, 0.f, 0.f};
    f32x4 acc[4][8];
#pragma unroll
    for (int i = 0; i < 4; ++i)
#pragma unroll
        for (int j = 0; j < 8; ++j) acc[i][j] = zero4;

    const int srow = lane >> 2;
    const int scol = (lane & 3) * 8;

    for (int kt = 0; kt < 8; ++kt) {
        const int kb = kt * 64;
#pragma unroll
        for (int p = 0; p < 2; ++p) {
#pragma unroll
            for (int i = 0; i < 2; ++i) {
                const int inst = wave * 2 + i;
                load_lds16(A + (row0 + inst * 16 + srow) * 512 + kb + p * 32 + scol,
                           &As[p * 4096 + inst * 512]);
            }
#pragma unroll
            for (int i = 0; i < 4; ++i) {
                const int inst = wave * 4 + i;
                load_lds16(Bw + (size_t)(inst * 16 + srow) * 512 + kb + p * 32 + scol,
                           &Bs[p * 8192 + inst * 512]);
            }
        }
        __syncthreads();
#pragma unroll
        for (int ks = 0; ks < 2; ++ks) {
            f16x8 af[4], bf[8];
#pragma unroll
            for (int i = 0; i < 4; ++i)
                af[i] = *(const f16x8*)&As[ks * 4096 + (wm + i * 16 + am) * 32 + ak];
#pragma unroll
            for (int j = 0; j < 8; ++j)
                bf[j] = *(const f16x8*)&Bs[ks * 8192 + (wn + j * 16 + am) * 32 + ak];
#pragma unroll
            for (int i = 0; i < 4; ++i)
#pragma unroll
                for (int j = 0; j < 8; ++j)
                    acc[i][j] = MFMA16(bf[j], af[i], acc[i][j]);
        }
        __syncthreads();
    }
    const int cc = akg * 4;
#pragma unroll
    for (int i = 0; i < 4; ++i) {
        const size_t row = row0 + wm + i * 16 + am;
#pragma unroll
        for (int j = 0; j < 8; ++j) {
            const int col = wn + j * 16 + cc;
            const float4 b4 = *(const float4*)(bias + col);
            f16x4 v;
            v[0] = (f16)gelu_f(acc[i][j][0] + b4.x);
            v[1] = (f16)gelu_f(acc[i][j][1] + b4.y);
            v[2] = (f16)gelu_f(acc[i][j][2] + b4.z);
            v[3] = (f16)gelu_f(acc[i][j][3] + b4.w);
            *(f16x4*)(C + row * 256 + col) = v;
        }
    }
}

// ---------------- fused tail: router + grouped fc3 + L4 + L5 + L6 ----------
// 64 rows/block, 4 waves; every phase is WAVE-LOCAL (reads only LDS written
// by the same wave) -> zero __syncthreads; within-wave LDS RAW ordered by
// compiler lgkmcnt.
__global__ __launch_bounds__(256, 2)
void k_tail(const f16* __restrict__ MID,
            const f16* __restrict__ W3f, const float* __restrict__ b3,
            const f16* __restrict__ W4f, const float* __restrict__ b4,
            const f16* __restrict__ W5f, const float* __restrict__ b5,
            const f16* __restrict__ W6p, const float* __restrict__ b6v,
            const f16* __restrict__ Wrf, const float* __restrict__ brv,
            float* __restrict__ OUT) {
    __shared__ f16 s_mid[64 * 264];     // mid_in tile, stride 264 (+8 pad)
    __shared__ float s_pw[64 * 20];     // 16 pathway weights + 4 group-sums
    __shared__ f16 s_mo[64 * 136];      // mid_out, stride 136
    __shared__ f16 s_h4[64 * 72];       // h4, stride 72
    __shared__ f16 s_h5[64 * 40];       // h5, stride 40
    const int tid = threadIdx.x, wave = tid >> 6, lane = tid & 63;
    const size_t r0 = (size_t)blockIdx.x * 64;
    const int am = lane & 15, akg = lane >> 4, ak = akg * 8;
    const int wr = wave * 16;
    const int crow = wr + akg * 4;
    const f32x4 zero4 = {0.f, 0.f, 0.f, 0.f};

    // phase 1: stage this wave's 16 rows of mid_in -> LDS (wave-local)
    {
        const int row = wr + (lane >> 2), seg = (lane & 3) * 64;
        const f16* src = MID + (r0 + row) * 256 + seg;
        f16* dst = s_mid + row * 264 + seg;
#pragma unroll
        for (int c = 0; c < 8; ++c)
            *(f16x8*)(dst + c * 8) = *(const f16x8*)(src + c * 8);
    }

    // phase 2: router logits + softmax across 16 lanes
    {
        f32x4 lacc = zero4;
#pragma unroll
        for (int ks = 0; ks < 8; ++ks) {
            f16x8 a = *(const f16x8*)(s_mid + (wr + am) * 264 + ks * 32 + ak);
            f16x8 b = *(const f16x8*)(Wrf + am * 256 + ks * 32 + ak);
            lacc = MFMA16(a, b, lacc);
        }
        const float brn = brv[am];
#pragma unroll
        for (int r = 0; r < 4; ++r) {
            float l = lacc[r] + brn;
            float mx = l;
#pragma unroll
            for (int m = 1; m <= 8; m <<= 1) mx = fmaxf(mx, __shfl_xor(mx, m));
            const float e = __expf(l - mx);
            float s = e;
#pragma unroll
            for (int m = 1; m <= 8; m <<= 1) s += __shfl_xor(s, m);
            const float p = e / s;
            float sg = p;
            sg += __shfl_xor(sg, 4);
            sg += __shfl_xor(sg, 8);
            s_pw[(crow + r) * 20 + am] = p;
            if (am < 4) s_pw[(crow + r) * 20 + 16 + am] = sg;
        }
    }

    // phase 3: grouped fc3 + pathway-weighted combine + gelu -> s_mo
    {
        f16x8 a3[4][2];
#pragma unroll
        for (int g = 0; g < 4; ++g)
#pragma unroll
            for (int kh = 0; kh < 2; ++kh)
                a3[g][kh] = *(const f16x8*)(s_mid + (wr + am) * 264 + g * 64 + kh * 32 + ak);
#pragma unroll
        for (int o = 0; o < 4; ++o) {
            float pwv[4][4], sgl[4];
#pragma unroll
            for (int r = 0; r < 4; ++r) {
                sgl[r] = s_pw[(crow + r) * 20 + 16 + o];
#pragma unroll
                for (int g = 0; g < 4; ++g)
                    pwv[g][r] = s_pw[(crow + r) * 20 + g * 4 + o];
            }
#pragma unroll
            for (int ctl = 0; ctl < 2; ++ctl) {
                const int ct = o * 2 + ctl;
                const int col = ct * 16 + am;
                const float bias = b3[col];
                f32x4 oacc;
#pragma unroll
                for (int r = 0; r < 4; ++r) oacc[r] = bias * sgl[r];
#pragma unroll
                for (int g = 0; g < 4; ++g) {
                    f32x4 t = zero4;
                    t = MFMA16(a3[g][0], *(const f16x8*)(W3f + (size_t)col * 256 + g * 64 + ak), t);
                    t = MFMA16(a3[g][1], *(const f16x8*)(W3f + (size_t)col * 256 + g * 64 + 32 + ak), t);
#pragma unroll
                    for (int r = 0; r < 4; ++r) oacc[r] += pwv[g][r] * t[r];
                }
#pragma unroll
                for (int r = 0; r < 4; ++r)
                    s_mo[(crow + r) * 136 + col] = (f16)gelu_f(oacc[r]);
            }
        }
    }

    // phase 4: L4
    {
        f16x8 a4[4];
#pragma unroll
        for (int ks = 0; ks < 4; ++ks)
            a4[ks] = *(const f16x8*)(s_mo + (wr + am) * 136 + ks * 32 + ak);
#pragma unroll
        for (int ct = 0; ct < 4; ++ct) {
            const int col = ct * 16 + am;
            f32x4 acc = zero4;
#pragma unroll
            for (int ks = 0; ks < 4; ++ks)
                acc = MFMA16(a4[ks], *(const f16x8*)(W4f + (size_t)col * 128 + ks * 32 + ak), acc);
            const float bias = b4[col];
#pragma unroll
            for (int r = 0; r < 4; ++r)
                s_h4[(crow + r) * 72 + col] = (f16)gelu_f(acc[r] + bias);
        }
    }

    // phase 5: L5
    {
        f16x8 a5[2];
#pragma unroll
        for (int ks = 0; ks < 2; ++ks)
            a5[ks] = *(const f16x8*)(s_h4 + (wr + am) * 72 + ks * 32 + ak);
#pragma unroll
        for (int ct = 0; ct < 2; ++ct) {
            const int col = ct * 16 + am;
            f32x4 acc = zero4;
#pragma unroll
            for (int ks = 0; ks < 2; ++ks)
                acc = MFMA16(a5[ks], *(const f16x8*)(W5f + (size_t)col * 64 + ks * 32 + ak), acc);
            const float bias = b5[col];
#pragma unroll
            for (int r = 0; r < 4; ++r)
                s_h5[(crow + r) * 40 + col] = (f16)gelu_f(acc[r] + bias);
        }
    }

    // phase 6: L6
    {
        f16x8 a6 = *(const f16x8*)(s_h5 + (wr + am) * 40 + ak);
        f16x8 bw = *(const f16x8*)(W6p + am * 32 + ak);
        f32x4 acc = MFMA16(a6, bw, zero4);
        if (am < 10) {
            const float bb = b6v[am];
#pragma unroll
            for (int r = 0; r < 4; ++r)
                OUT[(r0 + crow + r) * 10 + am] = acc[r] + bb;
        }
    }
}

extern "C" void kernel_launch(void* const* d_in, const int* in_sizes, int n_in,
                              void* d_out, int out_size, void* d_ws, size_t ws_size,
                              hipStream_t stream) {
    const float* x  = (const float*)d_in[0];
    const float* W1 = (const float*)d_in[1];
    const float* b1 = (const float*)d_in[2];
    const float* W2 = (const float*)d_in[3];
    const float* b2 = (const float*)d_in[4];
    const float* W3 = (const float*)d_in[5];
    const float* b3 = (const float*)d_in[6];
    const float* W4 = (const float*)d_in[7];
    const float* b4 = (const float*)d_in[8];
    const float* W5 = (const float*)d_in[9];
    const float* b5 = (const float*)d_in[10];
    const float* W6 = (const float*)d_in[11];
    const float* b6 = (const float*)d_in[12];
    const float* Wr = (const float*)d_in[13];
    const float* br = (const float*)d_in[14];
    float* out = (float*)d_out;

    const int M = in_sizes[0] / 784;    // 131072

    char* ws = (char*)d_ws;
    f16* W1p = (f16*)ws; ws += 512 * 832 * 2;
    f16* W2f = (f16*)ws; ws += 256 * 512 * 2;
    f16* W3f = (f16*)ws; ws += 128 * 256 * 2;
    f16* W4f = (f16*)ws; ws += 64 * 128 * 2;
    f16* W5f = (f16*)ws; ws += 32 * 64 * 2;
    f16* W6p = (f16*)ws; ws += 16 * 32 * 2;
    f16* Wrf = (f16*)ws; ws += 16 * 256 * 2;
    f16* H1  = (f16*)ws; ws += (size_t)M * 512 * 2; // 134 MB
    f16* MIDB= (f16*)ws; ws += (size_t)M * 256 * 2; // 67 MB

    k_prep<<<2362, 256, 0, stream>>>(W1, W2, W3, W4, W5, W6, Wr,
                                     W1p, W2f, W3f, W4f, W5f, W6p, Wrf);
    k_gemm1<<<(M / 128) * 2, 256, 0, stream>>>(x, W1p, b1, H1);
    k_gemm2<<<M / 128, 256, 0, stream>>>(H1, W2f, b2, MIDB);
    k_tail<<<M / 64, 256, 0, stream>>>(MIDB, W3f, b3, W4f, b4, W5f, b5,
                                       W6p, b6, Wrf, br, out);
}